// Round 13
// baseline (82.391 us; speedup 1.0000x reference)
//
#include <hip/hip_runtime.h>
#include <hip/hip_bf16.h>

#define DIM 768
#define LTOK 1024
#define NBATCH 32
#define KEEP 256

// Correctly-rounded f32 reciprocal robust to compile flags (matches np's
// hoisted `inv = 1/den` reciprocal-multiply chain, proven in R9).
__device__ __forceinline__ float recip_cr_f32(float b) {
    return (float)(1.0 / (double)b);
}

// term[c] = (c/768)*log(c/768 + 1e-9) in f64 — same expression as R9's
// in-kernel TERM, so downstream entropies stay bit-identical.
__global__ __launch_bounds__(256) void table_kernel(double* __restrict__ term) {
    int i = blockIdx.x * 256 + threadIdx.x;
    if (i <= DIM) {
        double p = (double)i / 768.0;
        term[i] = p * log(p + 1e-9);
    }
}

// 8 rows per wave: 4 row-pairs, register-double-buffered so pair i+1's 12
// dwordx4 loads fly under pair i's compute (latency amortized 4x).
// Lanes 0-31 -> even row of pair, 32-63 -> odd row.  24 elems per half-lane.
// R9-verified np binning chain (DO NOT TOUCH):
//   den = (mx-mn)+1e-19f ; inv = RN32(1/den) ; nrm = RN32(s*inv) ;
//   t = RN32(nrm*9) ; q = (int)t  [trunc==floor, q in 0..9 provable].
// Histogram: u64 10x6-bit pack, 1 pre-widen level, widen to 2x12-bit, 4-level
// butterfly; writes {lo,hi} packed counts per row (no f64 anywhere).
__global__ __launch_bounds__(256) void ent_kernel(const float* __restrict__ x,
                                                  ulonglong2* __restrict__ cnt) {
    int wave = blockIdx.x * 4 + (threadIdx.x >> 6);   // 0..4095
    int lane = threadIdx.x & 63;
    int g    = lane >> 5;                             // half-wave row select
    int il   = lane & 31;
    int row0 = wave * 8 + g;
    const float* p = x + (size_t)row0 * DIM + il * 4;

    float4 va[6], vb[6];
    #pragma unroll
    for (int j = 0; j < 6; ++j) va[j] = *(const float4*)(p + j * 128);

    #pragma unroll
    for (int i = 0; i < 4; ++i) {
        // prefetch next pair while computing this one
        if (i < 3) {
            const float* pn = p + (size_t)(i + 1) * 2 * DIM;
            #pragma unroll
            for (int j = 0; j < 6; ++j) vb[j] = *(const float4*)(pn + j * 128);
        }

        float mn = va[0].x, mx = va[0].x;
        #pragma unroll
        for (int j = 0; j < 6; ++j) {
            mn = fminf(fminf(fminf(mn, va[j].x), fminf(va[j].y, va[j].z)), va[j].w);
            mx = fmaxf(fmaxf(fmaxf(mx, va[j].x), fmaxf(va[j].y, va[j].z)), va[j].w);
        }
        #pragma unroll
        for (int off = 16; off > 0; off >>= 1) {
            mn = fminf(mn, __shfl_xor(mn, off, 64));
            mx = fmaxf(mx, __shfl_xor(mx, off, 64));
        }

        float den = (mx - mn) + 1e-19f;   // 1e-19 absorbed
        float inv = recip_cr_f32(den);    // RN32(1/den)

        unsigned long long pk = 0ull;     // 10 bins x 6 bits; per-lane max 24
        #define ACC(v) do { float s_  = (v) - mn;                            \
                            float nr_ = s_ * inv;    /* RN32, lone mul */    \
                            float t_  = nr_ * 9.0f;  /* RN32, lone mul */    \
                            unsigned q = (unsigned)t_; /* trunc==floor */    \
                            pk = (1ull << (6u * q)) + pk; } while (0)
        #pragma unroll
        for (int j = 0; j < 6; ++j) { ACC(va[j].x); ACC(va[j].y); ACC(va[j].z); ACC(va[j].w); }
        #undef ACC

        // one 6-bit-packed level first (sum <= 48 per field, no overflow)
        pk += __shfl_xor(pk, 1, 64);

        unsigned long long lo = 0ull, hi = 0ull;
        #pragma unroll
        for (int b = 0; b < 5; ++b) {
            lo |= ((pk >> (6 * b)) & 63ull) << (12 * b);
            hi |= ((pk >> (6 * (b + 5))) & 63ull) << (12 * b);
        }
        #pragma unroll
        for (int off = 2; off <= 16; off <<= 1) {
            lo += __shfl_xor(lo, off, 64);
            hi += __shfl_xor(hi, off, 64);
        }

        if (il == 0) {
            ulonglong2 c; c.x = lo; c.y = hi;
            cnt[row0 + i * 2] = c;
        }

        #pragma unroll
        for (int j = 0; j < 6; ++j) va[j] = vb[j];
    }
}

// Per (batch, chunk) block: entropies from packed counts (bit-identical
// formula/order), stable rank, outputs, AND fused gather: each block copies
// its own keepers' rows (LDS list; disjoint (n,rank) dst => deterministic).
__global__ __launch_bounds__(128) void rank_kernel(const float* __restrict__ x,
                                                   const ulonglong2* __restrict__ cnt,
                                                   const double* __restrict__ term,
                                                   float* __restrict__ out_xm,
                                                   float* __restrict__ out_mask,
                                                   float* __restrict__ out_restore) {
    __shared__ double se[LTOK];
    __shared__ double sterm[DIM + 1];
    __shared__ int klist[128];
    __shared__ int kcount;
    int n = blockIdx.x;      // 0..31
    int chunk = blockIdx.y;  // 0..7

    if (threadIdx.x == 0) kcount = 0;
    for (int i = threadIdx.x; i <= DIM; i += 128)
        sterm[i] = term[i];
    __syncthreads();

    for (int r = threadIdx.x; r < LTOK; r += 128) {
        ulonglong2 c = cnt[n * LTOK + r];
        unsigned long long lo = c.x, hi = c.y;
        double t0 = sterm[(lo      ) & 4095ull];
        double t1 = sterm[(lo >> 12) & 4095ull];
        double t2 = sterm[(lo >> 24) & 4095ull];
        double t3 = sterm[(lo >> 36) & 4095ull];
        double t4 = sterm[(lo >> 48) & 4095ull];
        double t5 = sterm[(hi      ) & 4095ull];
        double t6 = sterm[(hi >> 12) & 4095ull];
        double t7 = sterm[(hi >> 24) & 4095ull];
        double t8 = sterm[(hi >> 36) & 4095ull];
        double t9 = sterm[(hi >> 48) & 4095ull];
        // numpy pairwise order for n=10: tree over first 8, then +t8, +t9
        double s = ((t0 + t1) + (t2 + t3)) + ((t4 + t5) + (t6 + t7));
        s += t8;
        s += t9;
        se[r] = -s;
    }
    __syncthreads();

    int l = chunk * 128 + threadIdx.x;
    double e = se[l];
    int rank = 0;
    #pragma unroll 8
    for (int j = 0; j < LTOK; ++j) {
        double ej = se[j];
        rank += (int)((ej > e) | ((ej == e) & (j < l)));
    }
    out_restore[n * LTOK + l] = (float)rank;
    out_mask[n * LTOK + l]    = (rank < KEEP) ? 0.0f : 1.0f;
    if (rank < KEEP) {
        int idx = atomicAdd(&kcount, 1);       // LDS atomic
        klist[idx] = (l << 16) | rank;
    }
    __syncthreads();

    // fused gather: copy each keeper row (192 float4) with all 128 threads
    int nk = kcount;
    for (int e2 = 0; e2 < nk; ++e2) {
        int ent_ = klist[e2];
        int l2 = ent_ >> 16;
        int rk = ent_ & 0xFFFF;
        const float4* src = (const float4*)(x + ((size_t)n * LTOK + l2) * DIM);
        float4*       dst = (float4*)(out_xm + ((size_t)n * KEEP + rk) * DIM);
        dst[threadIdx.x] = src[threadIdx.x];
        if (threadIdx.x < 64)
            dst[128 + threadIdx.x] = src[128 + threadIdx.x];
    }
}

extern "C" void kernel_launch(void* const* d_in, const int* in_sizes, int n_in,
                              void* d_out, int out_size, void* d_ws, size_t ws_size,
                              hipStream_t stream) {
    const float* x = (const float*)d_in[0];

    // d_out is float32, outputs concatenated flat: x_masked | mask | ids_restore
    float* out = (float*)d_out;
    float* out_xm      = out;                                   // 32*256*768
    float* out_mask    = out + (size_t)NBATCH * KEEP * DIM;     // 32*1024
    float* out_restore = out_mask + (size_t)NBATCH * LTOK;      // 32*1024

    // ws: term table (8 KiB) | packed counts (32768 x 16 B)
    double*     ws_term = (double*)d_ws;
    ulonglong2* ws_cnt  = (ulonglong2*)((char*)d_ws + 8192);

    table_kernel<<<dim3(4), 256, 0, stream>>>(ws_term);
    ent_kernel<<<dim3(NBATCH * LTOK / 32), 256, 0, stream>>>(x, ws_cnt);
    rank_kernel<<<dim3(NBATCH, 8), 128, 0, stream>>>(x, ws_cnt, ws_term,
                                                     out_xm, out_mask, out_restore);
}

// Round 14
// 68.218 us; speedup vs baseline: 1.2078x; 1.2078x over previous
//
#include <hip/hip_runtime.h>
#include <hip/hip_bf16.h>

#define DIM 768
#define LTOK 1024
#define NBATCH 32
#define KEEP 256

// Correctly-rounded f32 reciprocal robust to compile flags (matches np's
// hoisted `inv = 1/den` reciprocal-multiply chain, proven in R9).
__device__ __forceinline__ float recip_cr_f32(float b) {
    return (float)(1.0 / (double)b);
}

// term[c] = (c/768)*log(c/768 + 1e-9) in f64 — same expression as R9's
// in-kernel TERM, so downstream entropies stay bit-identical.
__global__ __launch_bounds__(256) void table_kernel(double* __restrict__ term) {
    int i = blockIdx.x * 256 + threadIdx.x;
    if (i <= DIM) {
        double p = (double)i / 768.0;
        term[i] = p * log(p + 1e-9);
    }
}

// 8 rows per wave: 4 row-pairs, register-double-buffered so pair i+1's 12
// dwordx4 loads fly under pair i's compute (latency amortized 4x, proven R13).
// Lanes 0-31 -> even row of pair, 32-63 -> odd row.  24 elems per half-lane.
// R9-verified np binning chain (DO NOT TOUCH):
//   den = (mx-mn)+1e-19f ; inv = RN32(1/den) ; nrm = RN32(s*inv) ;
//   t = RN32(nrm*9) ; q = (int)t  [trunc==floor, q in 0..9 provable].
__global__ __launch_bounds__(256) void ent_kernel(const float* __restrict__ x,
                                                  ulonglong2* __restrict__ cnt) {
    int wave = blockIdx.x * 4 + (threadIdx.x >> 6);   // 0..4095
    int lane = threadIdx.x & 63;
    int g    = lane >> 5;                             // half-wave row select
    int il   = lane & 31;
    int row0 = wave * 8 + g;
    const float* p = x + (size_t)row0 * DIM + il * 4;

    float4 va[6], vb[6];
    #pragma unroll
    for (int j = 0; j < 6; ++j) va[j] = *(const float4*)(p + j * 128);

    #pragma unroll
    for (int i = 0; i < 4; ++i) {
        if (i < 3) {
            const float* pn = p + (size_t)(i + 1) * 2 * DIM;
            #pragma unroll
            for (int j = 0; j < 6; ++j) vb[j] = *(const float4*)(pn + j * 128);
        }

        float mn = va[0].x, mx = va[0].x;
        #pragma unroll
        for (int j = 0; j < 6; ++j) {
            mn = fminf(fminf(fminf(mn, va[j].x), fminf(va[j].y, va[j].z)), va[j].w);
            mx = fmaxf(fmaxf(fmaxf(mx, va[j].x), fmaxf(va[j].y, va[j].z)), va[j].w);
        }
        #pragma unroll
        for (int off = 16; off > 0; off >>= 1) {
            mn = fminf(mn, __shfl_xor(mn, off, 64));
            mx = fmaxf(mx, __shfl_xor(mx, off, 64));
        }

        float den = (mx - mn) + 1e-19f;   // 1e-19 absorbed
        float inv = recip_cr_f32(den);    // RN32(1/den)

        unsigned long long pk = 0ull;     // 10 bins x 6 bits; per-lane max 24
        #define ACC(v) do { float s_  = (v) - mn;                            \
                            float nr_ = s_ * inv;    /* RN32, lone mul */    \
                            float t_  = nr_ * 9.0f;  /* RN32, lone mul */    \
                            unsigned q = (unsigned)t_; /* trunc==floor */    \
                            pk = (1ull << (6u * q)) + pk; } while (0)
        #pragma unroll
        for (int j = 0; j < 6; ++j) { ACC(va[j].x); ACC(va[j].y); ACC(va[j].z); ACC(va[j].w); }
        #undef ACC

        // one 6-bit-packed level first (sum <= 48 per field, no overflow)
        pk += __shfl_xor(pk, 1, 64);

        unsigned long long lo = 0ull, hi = 0ull;
        #pragma unroll
        for (int b = 0; b < 5; ++b) {
            lo |= ((pk >> (6 * b)) & 63ull) << (12 * b);
            hi |= ((pk >> (6 * (b + 5))) & 63ull) << (12 * b);
        }
        #pragma unroll
        for (int off = 2; off <= 16; off <<= 1) {
            lo += __shfl_xor(lo, off, 64);
            hi += __shfl_xor(hi, off, 64);
        }

        if (il == 0) {
            ulonglong2 c; c.x = lo; c.y = hi;
            cnt[row0 + i * 2] = c;
        }

        #pragma unroll
        for (int j = 0; j < 6; ++j) va[j] = vb[j];
    }
}

// Per (batch, chunk) block: entropies from packed counts (bit-identical
// formula/order to R11), then the stable rank loop.  (Gather NOT fused —
// R13 proved the fused serial copy is a 10x regression.)
__global__ __launch_bounds__(128) void rank_kernel(const ulonglong2* __restrict__ cnt,
                                                   const double* __restrict__ term,
                                                   int* __restrict__ keep,
                                                   float* __restrict__ out_mask,
                                                   float* __restrict__ out_restore) {
    __shared__ double se[LTOK];
    __shared__ double sterm[DIM + 1];
    int n = blockIdx.x;      // 0..31
    int chunk = blockIdx.y;  // 0..7

    for (int i = threadIdx.x; i <= DIM; i += 128)
        sterm[i] = term[i];
    __syncthreads();

    for (int r = threadIdx.x; r < LTOK; r += 128) {
        ulonglong2 c = cnt[n * LTOK + r];
        unsigned long long lo = c.x, hi = c.y;
        double t0 = sterm[(lo      ) & 4095ull];
        double t1 = sterm[(lo >> 12) & 4095ull];
        double t2 = sterm[(lo >> 24) & 4095ull];
        double t3 = sterm[(lo >> 36) & 4095ull];
        double t4 = sterm[(lo >> 48) & 4095ull];
        double t5 = sterm[(hi      ) & 4095ull];
        double t6 = sterm[(hi >> 12) & 4095ull];
        double t7 = sterm[(hi >> 24) & 4095ull];
        double t8 = sterm[(hi >> 36) & 4095ull];
        double t9 = sterm[(hi >> 48) & 4095ull];
        // numpy pairwise order for n=10: tree over first 8, then +t8, +t9
        double s = ((t0 + t1) + (t2 + t3)) + ((t4 + t5) + (t6 + t7));
        s += t8;
        s += t9;
        se[r] = -s;
    }
    __syncthreads();

    int l = chunk * 128 + threadIdx.x;
    double e = se[l];
    int rank = 0;
    #pragma unroll 8
    for (int j = 0; j < LTOK; ++j) {
        double ej = se[j];
        rank += (int)((ej > e) | ((ej == e) & (j < l)));
    }
    out_restore[n * LTOK + l] = (float)rank;
    out_mask[n * LTOK + l]    = (rank < KEEP) ? 0.0f : 1.0f;
    if (rank < KEEP) keep[n * KEEP + rank] = l;   // ids_shuffle[rank] = l
}

// One wave per kept row: x_masked[n, r, :] = x[n, keep[n,r], :]  (f32 copy)
// 8192 independent waves — fully parallel, unlike the R13 fused version.
__global__ __launch_bounds__(256) void gather_kernel(const float* __restrict__ x,
                                                     const int* __restrict__ keep,
                                                     float* __restrict__ xm) {
    int r    = blockIdx.x * 4 + (threadIdx.x >> 6);  // 0..8191
    int lane = threadIdx.x & 63;
    int n = r >> 8;
    int k = r & 255;
    int src = keep[n * KEEP + k];
    const float* srow = x + ((size_t)n * LTOK + (size_t)src) * DIM;
    float* drow = xm + (size_t)r * DIM;
    #pragma unroll
    for (int t = 0; t < 3; ++t) {
        float4 v = *(const float4*)(srow + t * 256 + lane * 4);
        *(float4*)(drow + t * 256 + lane * 4) = v;
    }
}

extern "C" void kernel_launch(void* const* d_in, const int* in_sizes, int n_in,
                              void* d_out, int out_size, void* d_ws, size_t ws_size,
                              hipStream_t stream) {
    const float* x = (const float*)d_in[0];

    // d_out is float32, outputs concatenated flat: x_masked | mask | ids_restore
    float* out = (float*)d_out;
    float* out_xm      = out;                                   // 32*256*768
    float* out_mask    = out + (size_t)NBATCH * KEEP * DIM;     // 32*1024
    float* out_restore = out_mask + (size_t)NBATCH * LTOK;      // 32*1024

    // ws: term table (8 KiB) | packed counts (32768 x 16 B) | keep (32 KiB)
    double*     ws_term = (double*)d_ws;
    ulonglong2* ws_cnt  = (ulonglong2*)((char*)d_ws + 8192);
    int*        ws_keep = (int*)((char*)d_ws + 8192 + (size_t)NBATCH * LTOK * sizeof(ulonglong2));

    table_kernel<<<dim3(4), 256, 0, stream>>>(ws_term);
    ent_kernel<<<dim3(NBATCH * LTOK / 32), 256, 0, stream>>>(x, ws_cnt);
    rank_kernel<<<dim3(NBATCH, 8), 128, 0, stream>>>(ws_cnt, ws_term, ws_keep, out_mask, out_restore);
    gather_kernel<<<dim3(NBATCH * KEEP / 4), 256, 0, stream>>>(x, ws_keep, out_xm);
}

// Round 15
// 62.314 us; speedup vs baseline: 1.3222x; 1.0947x over previous
//
#include <hip/hip_runtime.h>
#include <hip/hip_bf16.h>

#define DIM 768
#define LTOK 1024
#define NBATCH 32
#define KEEP 256

// Correctly-rounded f32 reciprocal robust to compile flags (matches np's
// hoisted `inv = 1/den` reciprocal-multiply chain, proven in R9).
__device__ __forceinline__ float recip_cr_f32(float b) {
    return (float)(1.0 / (double)b);
}

// 8 rows per wave: 4 row-pairs, register-double-buffered (R13-proven).
// Term table built ONCE per block in LDS (same f64 expression as before ->
// bit-identical), entropy computed in-kernel; tail hidden by the pipeline.
// R9-verified np binning chain (DO NOT TOUCH):
//   den = (mx-mn)+1e-19f ; inv = RN32(1/den) ; nrm = RN32(s*inv) ;
//   t = RN32(nrm*9) ; q = (int)t  [trunc==floor, q in 0..9 provable].
__global__ __launch_bounds__(256) void ent_kernel(const float* __restrict__ x,
                                                  double* __restrict__ ent) {
    __shared__ double sterm[DIM + 1];
    // build term table: term[c] = (c/768)*log(c/768 + 1e-9)
    for (int i = threadIdx.x; i <= DIM; i += 256) {
        double p = (double)i / 768.0;
        sterm[i] = p * log(p + 1e-9);
    }
    __syncthreads();

    int wave = blockIdx.x * 4 + (threadIdx.x >> 6);   // 0..4095
    int lane = threadIdx.x & 63;
    int g    = lane >> 5;                             // half-wave row select
    int il   = lane & 31;
    int row0 = wave * 8 + g;
    const float* p = x + (size_t)row0 * DIM + il * 4;

    float4 va[6], vb[6];
    #pragma unroll
    for (int j = 0; j < 6; ++j) va[j] = *(const float4*)(p + j * 128);

    #pragma unroll
    for (int i = 0; i < 4; ++i) {
        if (i < 3) {
            const float* pn = p + (size_t)(i + 1) * 2 * DIM;
            #pragma unroll
            for (int j = 0; j < 6; ++j) vb[j] = *(const float4*)(pn + j * 128);
        }

        float mn = va[0].x, mx = va[0].x;
        #pragma unroll
        for (int j = 0; j < 6; ++j) {
            mn = fminf(fminf(fminf(mn, va[j].x), fminf(va[j].y, va[j].z)), va[j].w);
            mx = fmaxf(fmaxf(fmaxf(mx, va[j].x), fmaxf(va[j].y, va[j].z)), va[j].w);
        }
        #pragma unroll
        for (int off = 16; off > 0; off >>= 1) {
            mn = fminf(mn, __shfl_xor(mn, off, 64));
            mx = fmaxf(mx, __shfl_xor(mx, off, 64));
        }

        float den = (mx - mn) + 1e-19f;   // 1e-19 absorbed
        float inv = recip_cr_f32(den);    // RN32(1/den)

        unsigned long long pk = 0ull;     // 10 bins x 6 bits; per-lane max 24
        #define ACC(v) do { float s_  = (v) - mn;                            \
                            float nr_ = s_ * inv;    /* RN32, lone mul */    \
                            float t_  = nr_ * 9.0f;  /* RN32, lone mul */    \
                            unsigned q = (unsigned)t_; /* trunc==floor */    \
                            pk = (1ull << (6u * q)) + pk; } while (0)
        #pragma unroll
        for (int j = 0; j < 6; ++j) { ACC(va[j].x); ACC(va[j].y); ACC(va[j].z); ACC(va[j].w); }
        #undef ACC

        // one 6-bit-packed level first (sum <= 48 per field, no overflow)
        pk += __shfl_xor(pk, 1, 64);

        unsigned long long lo = 0ull, hi = 0ull;
        #pragma unroll
        for (int b = 0; b < 5; ++b) {
            lo |= ((pk >> (6 * b)) & 63ull) << (12 * b);
            hi |= ((pk >> (6 * (b + 5))) & 63ull) << (12 * b);
        }
        #pragma unroll
        for (int off = 2; off <= 16; off <<= 1) {
            lo += __shfl_xor(lo, off, 64);
            hi += __shfl_xor(hi, off, 64);
        }

        if (il == 0) {
            double t0 = sterm[(lo      ) & 4095ull];
            double t1 = sterm[(lo >> 12) & 4095ull];
            double t2 = sterm[(lo >> 24) & 4095ull];
            double t3 = sterm[(lo >> 36) & 4095ull];
            double t4 = sterm[(lo >> 48) & 4095ull];
            double t5 = sterm[(hi      ) & 4095ull];
            double t6 = sterm[(hi >> 12) & 4095ull];
            double t7 = sterm[(hi >> 24) & 4095ull];
            double t8 = sterm[(hi >> 36) & 4095ull];
            double t9 = sterm[(hi >> 48) & 4095ull];
            // numpy pairwise order for n=10: tree over first 8, then +t8, +t9
            double s = ((t0 + t1) + (t2 + t3)) + ((t4 + t5) + (t6 + t7));
            s += t8;
            s += t9;
            ent[row0 + i * 2] = -s;
        }

        #pragma unroll
        for (int j = 0; j < 6; ++j) va[j] = vb[j];
    }
}

// rank(l) = #{j : e_j > e_l} + #{j < l : e_j == e_l}  (== ids_restore)
__global__ __launch_bounds__(128) void rank_kernel(const double* __restrict__ ent,
                                                   int* __restrict__ keep,
                                                   float* __restrict__ out_mask,
                                                   float* __restrict__ out_restore) {
    __shared__ double se[LTOK];
    int n = blockIdx.x;      // 0..31
    int chunk = blockIdx.y;  // 0..7
    for (int i = threadIdx.x; i < LTOK; i += 128)
        se[i] = ent[n * LTOK + i];
    __syncthreads();

    int l = chunk * 128 + threadIdx.x;
    double e = se[l];
    int rank = 0;
    #pragma unroll 8
    for (int j = 0; j < LTOK; ++j) {
        double ej = se[j];
        rank += (int)((ej > e) | ((ej == e) & (j < l)));
    }
    out_restore[n * LTOK + l] = (float)rank;
    out_mask[n * LTOK + l]    = (rank < KEEP) ? 0.0f : 1.0f;
    if (rank < KEEP) keep[n * KEEP + rank] = l;   // ids_shuffle[rank] = l
}

// One wave per kept row: x_masked[n, r, :] = x[n, keep[n,r], :]  (f32 copy)
__global__ __launch_bounds__(256) void gather_kernel(const float* __restrict__ x,
                                                     const int* __restrict__ keep,
                                                     float* __restrict__ xm) {
    int r    = blockIdx.x * 4 + (threadIdx.x >> 6);  // 0..8191
    int lane = threadIdx.x & 63;
    int n = r >> 8;
    int k = r & 255;
    int src = keep[n * KEEP + k];
    const float* srow = x + ((size_t)n * LTOK + (size_t)src) * DIM;
    float* drow = xm + (size_t)r * DIM;
    #pragma unroll
    for (int t = 0; t < 3; ++t) {
        float4 v = *(const float4*)(srow + t * 256 + lane * 4);
        *(float4*)(drow + t * 256 + lane * 4) = v;
    }
}

extern "C" void kernel_launch(void* const* d_in, const int* in_sizes, int n_in,
                              void* d_out, int out_size, void* d_ws, size_t ws_size,
                              hipStream_t stream) {
    const float* x = (const float*)d_in[0];

    // d_out is float32, outputs concatenated flat: x_masked | mask | ids_restore
    float* out = (float*)d_out;
    float* out_xm      = out;                                   // 32*256*768
    float* out_mask    = out + (size_t)NBATCH * KEEP * DIM;     // 32*1024
    float* out_restore = out_mask + (size_t)NBATCH * LTOK;      // 32*1024

    // ws: ent f64 (256 KiB) | keep (32 KiB)
    double* ws_ent  = (double*)d_ws;
    int*    ws_keep = (int*)((char*)d_ws + (size_t)NBATCH * LTOK * sizeof(double));

    ent_kernel<<<dim3(NBATCH * LTOK / 32), 256, 0, stream>>>(x, ws_ent);
    rank_kernel<<<dim3(NBATCH, 8), 128, 0, stream>>>(ws_ent, ws_keep, out_mask, out_restore);
    gather_kernel<<<dim3(NBATCH * KEEP / 4), 256, 0, stream>>>(x, ws_keep, out_xm);
}

// Round 16
// 62.290 us; speedup vs baseline: 1.3227x; 1.0004x over previous
//
#include <hip/hip_runtime.h>
#include <hip/hip_bf16.h>

#define DIM 768
#define LTOK 1024
#define NBATCH 32
#define KEEP 256

// Correctly-rounded f32 reciprocal robust to compile flags (matches np's
// hoisted `inv = 1/den` reciprocal-multiply chain, proven in R9).
__device__ __forceinline__ float recip_cr_f32(float b) {
    return (float)(1.0 / (double)b);
}

// 8 rows per wave: 4 row-pairs, register-double-buffered (R13-proven).
// Term table built ONCE per block in LDS (same f64 expression -> bit-identical).
// R9-verified np binning chain (DO NOT TOUCH):
//   den = (mx-mn)+1e-19f ; inv = RN32(1/den) ; nrm = RN32(s*inv) ;
//   t = RN32(nrm*9) ; q = (int)t  [trunc==floor, q in 0..9 provable].
__global__ __launch_bounds__(256) void ent_kernel(const float* __restrict__ x,
                                                  double* __restrict__ ent) {
    __shared__ double sterm[DIM + 1];
    for (int i = threadIdx.x; i <= DIM; i += 256) {
        double p = (double)i / 768.0;
        sterm[i] = p * log(p + 1e-9);
    }
    __syncthreads();

    int wave = blockIdx.x * 4 + (threadIdx.x >> 6);   // 0..4095
    int lane = threadIdx.x & 63;
    int g    = lane >> 5;                             // half-wave row select
    int il   = lane & 31;
    int row0 = wave * 8 + g;
    const float* p = x + (size_t)row0 * DIM + il * 4;

    float4 va[6], vb[6];
    #pragma unroll
    for (int j = 0; j < 6; ++j) va[j] = *(const float4*)(p + j * 128);

    #pragma unroll
    for (int i = 0; i < 4; ++i) {
        if (i < 3) {
            const float* pn = p + (size_t)(i + 1) * 2 * DIM;
            #pragma unroll
            for (int j = 0; j < 6; ++j) vb[j] = *(const float4*)(pn + j * 128);
        }

        float mn = va[0].x, mx = va[0].x;
        #pragma unroll
        for (int j = 0; j < 6; ++j) {
            mn = fminf(fminf(fminf(mn, va[j].x), fminf(va[j].y, va[j].z)), va[j].w);
            mx = fmaxf(fmaxf(fmaxf(mx, va[j].x), fmaxf(va[j].y, va[j].z)), va[j].w);
        }
        #pragma unroll
        for (int off = 16; off > 0; off >>= 1) {
            mn = fminf(mn, __shfl_xor(mn, off, 64));
            mx = fmaxf(mx, __shfl_xor(mx, off, 64));
        }

        float den = (mx - mn) + 1e-19f;   // 1e-19 absorbed
        float inv = recip_cr_f32(den);    // RN32(1/den)

        unsigned long long pk = 0ull;     // 10 bins x 6 bits; per-lane max 24
        #define ACC(v) do { float s_  = (v) - mn;                            \
                            float nr_ = s_ * inv;    /* RN32, lone mul */    \
                            float t_  = nr_ * 9.0f;  /* RN32, lone mul */    \
                            unsigned q = (unsigned)t_; /* trunc==floor */    \
                            pk = (1ull << (6u * q)) + pk; } while (0)
        #pragma unroll
        for (int j = 0; j < 6; ++j) { ACC(va[j].x); ACC(va[j].y); ACC(va[j].z); ACC(va[j].w); }
        #undef ACC

        pk += __shfl_xor(pk, 1, 64);      // 6-bit level, sums <= 48

        unsigned long long lo = 0ull, hi = 0ull;
        #pragma unroll
        for (int b = 0; b < 5; ++b) {
            lo |= ((pk >> (6 * b)) & 63ull) << (12 * b);
            hi |= ((pk >> (6 * (b + 5))) & 63ull) << (12 * b);
        }
        #pragma unroll
        for (int off = 2; off <= 16; off <<= 1) {
            lo += __shfl_xor(lo, off, 64);
            hi += __shfl_xor(hi, off, 64);
        }

        if (il == 0) {
            double t0 = sterm[(lo      ) & 4095ull];
            double t1 = sterm[(lo >> 12) & 4095ull];
            double t2 = sterm[(lo >> 24) & 4095ull];
            double t3 = sterm[(lo >> 36) & 4095ull];
            double t4 = sterm[(lo >> 48) & 4095ull];
            double t5 = sterm[(hi      ) & 4095ull];
            double t6 = sterm[(hi >> 12) & 4095ull];
            double t7 = sterm[(hi >> 24) & 4095ull];
            double t8 = sterm[(hi >> 36) & 4095ull];
            double t9 = sterm[(hi >> 48) & 4095ull];
            // numpy pairwise order: tree over first 8, then +t8, +t9
            double s = ((t0 + t1) + (t2 + t3)) + ((t4 + t5) + (t6 + t7));
            s += t8;
            s += t9;
            ent[row0 + i * 2] = -s;
        }

        #pragma unroll
        for (int j = 0; j < 6; ++j) va[j] = vb[j];
    }
}

// rank(l) = #{j : e_j > e_l} + #{j < l : e_j == e_l}  (== ids_restore)
__global__ __launch_bounds__(128) void rank_kernel(const double* __restrict__ ent,
                                                   int* __restrict__ keep,
                                                   float* __restrict__ out_mask,
                                                   float* __restrict__ out_restore) {
    __shared__ double se[LTOK];
    int n = blockIdx.x;      // 0..31
    int chunk = blockIdx.y;  // 0..7
    for (int i = threadIdx.x; i < LTOK; i += 128)
        se[i] = ent[n * LTOK + i];
    __syncthreads();

    int l = chunk * 128 + threadIdx.x;
    double e = se[l];
    int rank = 0;
    #pragma unroll 8
    for (int j = 0; j < LTOK; ++j) {
        double ej = se[j];
        rank += (int)((ej > e) | ((ej == e) & (j < l)));
    }
    out_restore[n * LTOK + l] = (float)rank;
    out_mask[n * LTOK + l]    = (rank < KEEP) ? 0.0f : 1.0f;
    if (rank < KEEP) keep[n * KEEP + rank] = l;   // ids_shuffle[rank] = l
}

// 8 rows per 256-thr block (2 per wave).  The 8 keep indices arrive via one
// coalesced 8-lane load -> LDS (no per-wave dependent scalar chain); each
// wave issues all 6 row loads before any store (ILP batch).
__global__ __launch_bounds__(256) void gather_kernel(const float* __restrict__ x,
                                                     const int* __restrict__ keep,
                                                     float* __restrict__ xm) {
    __shared__ int sidx[8];
    int r0 = blockIdx.x * 8;                  // 8 | KEEP => one n per block
    if (threadIdx.x < 8) sidx[threadIdx.x] = keep[r0 + threadIdx.x];
    __syncthreads();

    int wv   = threadIdx.x >> 6;
    int lane = threadIdx.x & 63;
    int rA = r0 + wv * 2, rB = rA + 1;
    int n  = rA >> 8;
    int srcA = sidx[wv * 2], srcB = sidx[wv * 2 + 1];
    const float4* sA = (const float4*)(x + ((size_t)n * LTOK + (size_t)srcA) * DIM);
    const float4* sB = (const float4*)(x + ((size_t)n * LTOK + (size_t)srcB) * DIM);
    float4 a0 = sA[lane], a1 = sA[lane + 64], a2 = sA[lane + 128];
    float4 b0 = sB[lane], b1 = sB[lane + 64], b2 = sB[lane + 128];
    float4* dA = (float4*)(xm + (size_t)rA * DIM);
    float4* dB = (float4*)(xm + (size_t)rB * DIM);
    dA[lane] = a0; dA[lane + 64] = a1; dA[lane + 128] = a2;
    dB[lane] = b0; dB[lane + 64] = b1; dB[lane + 128] = b2;
}

extern "C" void kernel_launch(void* const* d_in, const int* in_sizes, int n_in,
                              void* d_out, int out_size, void* d_ws, size_t ws_size,
                              hipStream_t stream) {
    const float* x = (const float*)d_in[0];

    // d_out is float32, outputs concatenated flat: x_masked | mask | ids_restore
    float* out = (float*)d_out;
    float* out_xm      = out;                                   // 32*256*768
    float* out_mask    = out + (size_t)NBATCH * KEEP * DIM;     // 32*1024
    float* out_restore = out_mask + (size_t)NBATCH * LTOK;      // 32*1024

    // ws: ent f64 (256 KiB) | keep (32 KiB)
    double* ws_ent  = (double*)d_ws;
    int*    ws_keep = (int*)((char*)d_ws + (size_t)NBATCH * LTOK * sizeof(double));

    ent_kernel<<<dim3(NBATCH * LTOK / 32), 256, 0, stream>>>(x, ws_ent);
    rank_kernel<<<dim3(NBATCH, 8), 128, 0, stream>>>(ws_ent, ws_keep, out_mask, out_restore);
    gather_kernel<<<dim3(NBATCH * KEEP / 8), 256, 0, stream>>>(x, ws_keep, out_xm);
}

// Round 17
// 46.003 us; speedup vs baseline: 1.7910x; 1.3540x over previous
//
#include <hip/hip_runtime.h>
#include <hip/hip_bf16.h>

#define DIM 768
#define LTOK 1024
#define NBATCH 32
#define KEEP 256

// Correctly-rounded f32 reciprocal robust to compile flags (matches np's
// hoisted `inv = 1/den` reciprocal-multiply chain, proven in R9).
__device__ __forceinline__ float recip_cr_f32(float b) {
    return (float)(1.0 / (double)b);
}

// 8 rows per wave: 4 row-pairs, register-double-buffered (R13-proven ~17us).
// Term table built ONCE per block in LDS (same f64 expression -> bit-identical).
// R9-verified np binning chain (DO NOT TOUCH):
//   den = (mx-mn)+1e-19f ; inv = RN32(1/den) ; nrm = RN32(s*inv) ;
//   t = RN32(nrm*9) ; q = (int)t  [trunc==floor, q in 0..9 provable].
__global__ __launch_bounds__(256) void ent_kernel(const float* __restrict__ x,
                                                  double* __restrict__ ent) {
    __shared__ double sterm[DIM + 1];
    for (int i = threadIdx.x; i <= DIM; i += 256) {
        double p = (double)i / 768.0;
        sterm[i] = p * log(p + 1e-9);
    }
    __syncthreads();

    int wave = blockIdx.x * 4 + (threadIdx.x >> 6);   // 0..4095
    int lane = threadIdx.x & 63;
    int g    = lane >> 5;                             // half-wave row select
    int il   = lane & 31;
    int row0 = wave * 8 + g;
    const float* p = x + (size_t)row0 * DIM + il * 4;

    float4 va[6], vb[6];
    #pragma unroll
    for (int j = 0; j < 6; ++j) va[j] = *(const float4*)(p + j * 128);

    #pragma unroll
    for (int i = 0; i < 4; ++i) {
        if (i < 3) {
            const float* pn = p + (size_t)(i + 1) * 2 * DIM;
            #pragma unroll
            for (int j = 0; j < 6; ++j) vb[j] = *(const float4*)(pn + j * 128);
        }

        float mn = va[0].x, mx = va[0].x;
        #pragma unroll
        for (int j = 0; j < 6; ++j) {
            mn = fminf(fminf(fminf(mn, va[j].x), fminf(va[j].y, va[j].z)), va[j].w);
            mx = fmaxf(fmaxf(fmaxf(mx, va[j].x), fmaxf(va[j].y, va[j].z)), va[j].w);
        }
        #pragma unroll
        for (int off = 16; off > 0; off >>= 1) {
            mn = fminf(mn, __shfl_xor(mn, off, 64));
            mx = fmaxf(mx, __shfl_xor(mx, off, 64));
        }

        float den = (mx - mn) + 1e-19f;   // 1e-19 absorbed
        float inv = recip_cr_f32(den);    // RN32(1/den)

        unsigned long long pk = 0ull;     // 10 bins x 6 bits; per-lane max 24
        #define ACC(v) do { float s_  = (v) - mn;                            \
                            float nr_ = s_ * inv;    /* RN32, lone mul */    \
                            float t_  = nr_ * 9.0f;  /* RN32, lone mul */    \
                            unsigned q = (unsigned)t_; /* trunc==floor */    \
                            pk = (1ull << (6u * q)) + pk; } while (0)
        #pragma unroll
        for (int j = 0; j < 6; ++j) { ACC(va[j].x); ACC(va[j].y); ACC(va[j].z); ACC(va[j].w); }
        #undef ACC

        pk += __shfl_xor(pk, 1, 64);      // 6-bit level, sums <= 48

        unsigned long long lo = 0ull, hi = 0ull;
        #pragma unroll
        for (int b = 0; b < 5; ++b) {
            lo |= ((pk >> (6 * b)) & 63ull) << (12 * b);
            hi |= ((pk >> (6 * (b + 5))) & 63ull) << (12 * b);
        }
        #pragma unroll
        for (int off = 2; off <= 16; off <<= 1) {
            lo += __shfl_xor(lo, off, 64);
            hi += __shfl_xor(hi, off, 64);
        }

        if (il == 0) {
            double t0 = sterm[(lo      ) & 4095ull];
            double t1 = sterm[(lo >> 12) & 4095ull];
            double t2 = sterm[(lo >> 24) & 4095ull];
            double t3 = sterm[(lo >> 36) & 4095ull];
            double t4 = sterm[(lo >> 48) & 4095ull];
            double t5 = sterm[(hi      ) & 4095ull];
            double t6 = sterm[(hi >> 12) & 4095ull];
            double t7 = sterm[(hi >> 24) & 4095ull];
            double t8 = sterm[(hi >> 36) & 4095ull];
            double t9 = sterm[(hi >> 48) & 4095ull];
            // numpy pairwise order: tree over first 8, then +t8, +t9
            double s = ((t0 + t1) + (t2 + t3)) + ((t4 + t5) + (t6 + t7));
            s += t8;
            s += t9;
            ent[row0 + i * 2] = -s;
        }

        #pragma unroll
        for (int j = 0; j < 6; ++j) va[j] = vb[j];
    }
}

// Fused rank + gather.  256 threads/block, grid (32, 8).
// Rank: 2 threads per token split the 1024-iter compare loop (j<512 / j>=512),
// partials combined via LDS -> half the chain, 2x the waves vs R12.
// Gather: keepers among this block's 128 tokens (avg 32) copied by 4 waves
// with a 2-deep software pipeline (next row's loads before current stores).
// Unique (n,rank) destinations => deterministic regardless of klist order.
__global__ __launch_bounds__(256) void rankgather_kernel(const double* __restrict__ ent,
                                                         const float* __restrict__ x,
                                                         float* __restrict__ out_xm,
                                                         float* __restrict__ out_mask,
                                                         float* __restrict__ out_restore) {
    __shared__ double se[LTOK];
    __shared__ int pr[256];
    __shared__ int klist[128];
    __shared__ int kcount;
    int n = blockIdx.x;      // 0..31
    int chunk = blockIdx.y;  // 0..7
    int tid = threadIdx.x;

    if (tid == 0) kcount = 0;
    for (int i = tid; i < LTOK; i += 256)
        se[i] = ent[n * LTOK + i];
    __syncthreads();

    int t    = tid & 127;            // token within chunk
    int half = tid >> 7;             // j-range half
    int l    = chunk * 128 + t;
    double e = se[l];
    int j0 = half * 512;
    int partial = 0;
    #pragma unroll 8
    for (int j = j0; j < j0 + 512; ++j) {
        double ej = se[j];
        partial += (int)((ej > e) | ((ej == e) & (j < l)));
    }
    pr[tid] = partial;
    __syncthreads();

    if (tid < 128) {
        int rank = pr[tid] + pr[tid + 128];
        out_restore[n * LTOK + l] = (float)rank;
        out_mask[n * LTOK + l]    = (rank < KEEP) ? 0.0f : 1.0f;
        if (rank < KEEP) {
            int idx = atomicAdd(&kcount, 1);
            klist[idx] = (l << 16) | rank;
        }
    }
    __syncthreads();

    // gather: 4 waves, wave wv takes klist[wv], klist[wv+4], ...
    int nk   = kcount;
    int wv   = tid >> 6;
    int lane = tid & 63;
    const float4* xb = (const float4*)(x + (size_t)n * LTOK * DIM);
    float4*       ob = (float4*)(out_xm + (size_t)n * KEEP * DIM);

    int i = wv;
    float4 a0, a1, a2;
    int rkA = 0;
    if (i < nk) {
        int en = klist[i];
        const float4* s = xb + (size_t)(en >> 16) * (DIM / 4);
        rkA = en & 0xFFFF;
        a0 = s[lane]; a1 = s[lane + 64]; a2 = s[lane + 128];
    }
    while (i < nk) {
        int j = i + 4;
        float4 b0, b1, b2;
        int rkB = 0;
        if (j < nk) {
            int en = klist[j];
            const float4* s = xb + (size_t)(en >> 16) * (DIM / 4);
            rkB = en & 0xFFFF;
            b0 = s[lane]; b1 = s[lane + 64]; b2 = s[lane + 128];
        }
        float4* d = ob + (size_t)rkA * (DIM / 4);
        d[lane] = a0; d[lane + 64] = a1; d[lane + 128] = a2;
        a0 = b0; a1 = b1; a2 = b2; rkA = rkB;
        i = j;
    }
}

extern "C" void kernel_launch(void* const* d_in, const int* in_sizes, int n_in,
                              void* d_out, int out_size, void* d_ws, size_t ws_size,
                              hipStream_t stream) {
    const float* x = (const float*)d_in[0];

    // d_out is float32, outputs concatenated flat: x_masked | mask | ids_restore
    float* out = (float*)d_out;
    float* out_xm      = out;                                   // 32*256*768
    float* out_mask    = out + (size_t)NBATCH * KEEP * DIM;     // 32*1024
    float* out_restore = out_mask + (size_t)NBATCH * LTOK;      // 32*1024

    // ws: ent f64 (256 KiB)
    double* ws_ent = (double*)d_ws;

    ent_kernel<<<dim3(NBATCH * LTOK / 32), 256, 0, stream>>>(x, ws_ent);
    rankgather_kernel<<<dim3(NBATCH, 8), 256, 0, stream>>>(ws_ent, x, out_xm, out_mask, out_restore);
}